// Round 3
// baseline (895.428 us; speedup 1.0000x reference)
//
#include <hip/hip_runtime.h>

// ---------------------------------------------------------------------------
// MultiDiscreteACTLayer: B=131072 rows, D=256.
// Per row: 8 users x 16 sc logits + 8 heads x 10 pow logits = 208 dots of 256.
// JAX threefry, PARTITIONABLE semantics (jax>=0.4.36 default):
//   split(key,8)[u] = threefry2x32(key, (0, u))          (foldlike, both words)
//   fold_in(key, d) = threefry2x32(key, (0, d))          (both words)
//   random_bits 32-bit, element i (flat row-major, size < 2^32):
//       (b1, b2) = threefry2x32(key, (0, i));  bits = b1 ^ b2
// Output (float32): actions (B,16) | logp_sum (B,1) | avail (B,16).
// ---------------------------------------------------------------------------

#define B_TOTAL 131072
#define NCOL    208      // 8 users * (16 sc + 10 pow)
#define NCOLP   256      // padded column count for uniform 4x4 tiling
#define TINYF   1.17549435e-38f

struct TF2 { unsigned a, b; };

__host__ __device__ constexpr unsigned rotl_(unsigned x, int r) {
  return (x << r) | (x >> (32 - r));
}

// Threefry-2x32, 20 rounds, exactly as JAX/Random123.
__host__ __device__ constexpr TF2 tf2(unsigned k0, unsigned k1, unsigned x0, unsigned x1) {
  unsigned ks0 = k0, ks1 = k1, ks2 = k0 ^ k1 ^ 0x1BD11BDAu;
  x0 += ks0; x1 += ks1;
  x0 += x1; x1 = rotl_(x1, 13); x1 ^= x0;
  x0 += x1; x1 = rotl_(x1, 15); x1 ^= x0;
  x0 += x1; x1 = rotl_(x1, 26); x1 ^= x0;
  x0 += x1; x1 = rotl_(x1,  6); x1 ^= x0;
  x0 += ks1; x1 += ks2 + 1u;
  x0 += x1; x1 = rotl_(x1, 17); x1 ^= x0;
  x0 += x1; x1 = rotl_(x1, 29); x1 ^= x0;
  x0 += x1; x1 = rotl_(x1, 16); x1 ^= x0;
  x0 += x1; x1 = rotl_(x1, 24); x1 ^= x0;
  x0 += ks2; x1 += ks0 + 2u;
  x0 += x1; x1 = rotl_(x1, 13); x1 ^= x0;
  x0 += x1; x1 = rotl_(x1, 15); x1 ^= x0;
  x0 += x1; x1 = rotl_(x1, 26); x1 ^= x0;
  x0 += x1; x1 = rotl_(x1,  6); x1 ^= x0;
  x0 += ks0; x1 += ks1 + 3u;
  x0 += x1; x1 = rotl_(x1, 17); x1 ^= x0;
  x0 += x1; x1 = rotl_(x1, 29); x1 ^= x0;
  x0 += x1; x1 = rotl_(x1, 16); x1 ^= x0;
  x0 += x1; x1 = rotl_(x1, 24); x1 ^= x0;
  x0 += ks1; x1 += ks2 + 4u;
  x0 += x1; x1 = rotl_(x1, 13); x1 ^= x0;
  x0 += x1; x1 = rotl_(x1, 15); x1 ^= x0;
  x0 += x1; x1 = rotl_(x1, 26); x1 ^= x0;
  x0 += x1; x1 = rotl_(x1,  6); x1 ^= x0;
  x0 += ks2; x1 += ks0 + 5u;
  return TF2{x0, x1};
}

// foldlike derivation from root key (0, 42)
__host__ __device__ constexpr unsigned key_a(unsigned d) { return tf2(0u, 42u, 0u, d).a; }
__host__ __device__ constexpr unsigned key_b(unsigned d) { return tf2(0u, 42u, 0u, d).b; }

// sc_keys[u] = split(key(42), 8)[u]  (partitionable/foldlike)
__device__ const unsigned g_SK0[8] = {
  key_a(0), key_a(1), key_a(2), key_a(3), key_a(4), key_a(5), key_a(6), key_a(7)
};
__device__ const unsigned g_SK1[8] = {
  key_b(0), key_b(1), key_b(2), key_b(3), key_b(4), key_b(5), key_b(6), key_b(7)
};
// pow_key = fold_in(key(42), 999)
constexpr unsigned PK0 = key_a(999);
constexpr unsigned PK1 = key_b(999);

// JAX gumbel from raw bits, fp32 ops replicated; logs via double (correctly
// rounded fp32 result).
__device__ __forceinline__ float gumbelf(unsigned bits) {
  float u = __uint_as_float((bits >> 9) | 0x3f800000u) - 1.0f;   // [0,1)
  u = u + TINYF;               // u*(1-tiny)+tiny with (1-tiny)==1.0f in fp32
  u = fmaxf(TINYF, u);
  float nl = -(float)log((double)u);       // -log(u) > 0
  return -(float)log((double)nl);
}

// ---------------------------------------------------------------------------
// Kernel 0: repack W_sc (8,256,16) + W_pow (8,256,10) -> Wp[k][c], c in [0,256)
// (cols 208..255 zero), plus packed bias bp[256]. Column c = u*26 + n,
// n<16 -> sc logit n, n in 16..25 -> pow logit n-16.
// ---------------------------------------------------------------------------
__global__ void repack_kernel(const float* __restrict__ Wsc, const float* __restrict__ bsc,
                              const float* __restrict__ Wpow, const float* __restrict__ bpow,
                              float* __restrict__ Wp, float* __restrict__ bp) {
  int t = blockIdx.x * 256 + threadIdx.x;   // [0, 65792)
  if (t < 65536) {
    int k = t >> 8, c = t & 255;
    float v = 0.f;
    if (c < NCOL) {
      int u = c / 26, n = c % 26;
      v = (n < 16) ? Wsc[(u * 256 + k) * 16 + n]
                   : Wpow[(u * 256 + k) * 10 + (n - 16)];
    }
    Wp[k * NCOLP + c] = v;
  } else {
    int c = t - 65536;
    float v = 0.f;
    if (c < NCOL) {
      int u = c / 26, n = c % 26;
      v = (n < 16) ? bsc[u * 16 + n] : bpow[u * 10 + (n - 16)];
    }
    bp[c] = v;
  }
}

// ---------------------------------------------------------------------------
// Main kernel: each block handles 16 consecutive rows.
// Phase A: fp64-accum GEMM 16 rows x 256 padded cols (4x4 register tiles).
// Phase B: threefry+gumbel into LDS (partitionable: bits = w0 ^ w1).
// Phase C: 16 lanes per row: sc masked scan (8 users) + pow heads (8).
// ---------------------------------------------------------------------------
__global__ __launch_bounds__(256) void act_kernel(
    const float* __restrict__ x, const int* __restrict__ avail,
    const float* __restrict__ Wp, const float* __restrict__ bp,
    float* __restrict__ out) {
  __shared__ __align__(16) float xs[16][256];
  __shared__ float lg[16][NCOL];
  __shared__ float gg[16][NCOL];

  const int t = threadIdx.x;
  const int b0 = blockIdx.x * 16;

  // ---- load x tile (16 rows x 256) as float4 ----
#pragma unroll
  for (int i = 0; i < 4; ++i) {
    int flat = t + 256 * i;            // float4 index, [0,1024)
    int r = flat >> 6;                 // 64 float4 per row
    int kq = flat & 63;
    ((float4*)(&xs[r][0]))[kq] = ((const float4*)(x + (size_t)(b0 + r) * 256))[kq];
  }
  __syncthreads();

  // ---- Phase A: GEMM, fp64 accumulate ----
  {
    const int tr = t >> 6;             // row-group 0..3 (== wave id)
    const int tc = t & 63;             // col-group 0..63
    double acc[4][4] = {};
    const float4* wrow = (const float4*)Wp + tc;   // + k*64 each step
#pragma unroll 4
    for (int k = 0; k < 256; ++k) {
      float4 w4 = wrow[k * 64];
      double w0 = (double)w4.x, w1 = (double)w4.y,
             w2 = (double)w4.z, w3 = (double)w4.w;
#pragma unroll
      for (int rr = 0; rr < 4; ++rr) {
        double xv = (double)xs[tr * 4 + rr][k];
        acc[rr][0] = fma(xv, w0, acc[rr][0]);
        acc[rr][1] = fma(xv, w1, acc[rr][1]);
        acc[rr][2] = fma(xv, w2, acc[rr][2]);
        acc[rr][3] = fma(xv, w3, acc[rr][3]);
      }
    }
#pragma unroll
    for (int rr = 0; rr < 4; ++rr)
#pragma unroll
      for (int cc = 0; cc < 4; ++cc) {
        int c = tc * 4 + cc;
        if (c < NCOL)
          lg[tr * 4 + rr][c] = (float)(acc[rr][cc] + (double)bp[c]);
      }
  }

  // ---- Phase B: gumbels, partitionable counter mode (bits = w0 ^ w1) ----
  // 16 rows x 208 cols = 3328 = 13 * 256 elements.
  // sc element (user u, row gb, cat n):   i = gb*16+n,        key SK[u]
  // pow element (row gb, head h, cat j):  i = gb*80+h*10+j,   key PK
#pragma unroll
  for (int i = 0; i < 13; ++i) {
    int idx = t + 256 * i;             // [0, 3328)
    int row = idx / 208, c = idx % 208;
    int u = c / 26, n = c % 26;
    unsigned gbr = (unsigned)(b0 + row);
    unsigned k0, k1, cnt;
    if (n < 16) { k0 = g_SK0[u]; k1 = g_SK1[u]; cnt = gbr * 16u + (unsigned)n; }
    else        { k0 = PK0;      k1 = PK1;      cnt = gbr * 80u + (unsigned)(u * 10 + n - 16); }
    TF2 r = tf2(k0, k1, 0u, cnt);
    gg[row][c] = gumbelf(r.a ^ r.b);
  }
  __syncthreads();

  // ---- Phase C: sampling. 16 lanes per row. ----
  const int row = t >> 4;
  const int lane = t & 15;
  const int gb = b0 + row;
  const int av = avail[gb * 16 + lane];   // my lane's avail column
  int stat = 0;                           // sc_stat for category `lane`
  double lpsum = 0.0;
  float my_act = 0.0f;

  // sc scan: 8 users, sequential (sc_stat dependency)
  for (int u = 0; u < 8; ++u) {
    float logit = lg[row][u * 26 + lane];
    float ml = (stat < 2) ? logit : -1e10f;          // masked logit
    float y = ml + gg[row][u * 26 + lane];           // gumbel-perturbed
    // argmax (first index on tie)
    float v = y; int idx = lane;
    for (int off = 8; off; off >>= 1) {
      float v2 = __shfl_xor(v, off, 16);
      int i2 = __shfl_xor(idx, off, 16);
      if (v2 > v || (v2 == v && i2 < idx)) { v = v2; idx = i2; }
    }
    // log-softmax denom over masked logits
    float m = ml;
    for (int off = 8; off; off >>= 1) m = fmaxf(m, __shfl_xor(m, off, 16));
    float sh = ml - m;                               // fp32 shifted
    double s = exp((double)sh);                      // exp(-1e10)=0 for masked
    for (int off = 8; off; off >>= 1) s += __shfl_xor(s, off, 16);
    float sha = __shfl(sh, idx, 16);
    double lp = (double)sha - log(s);
    int au = __shfl(av, u, 16);
    if (au > 0) {
      lpsum += lp;
      if (lane == idx) stat += 1;                    // sc_stat update
    }
    if (lane == u) my_act = (au > 0) ? (float)idx : -1.0f;
  }

  // pow heads: independent
  for (int h = 0; h < 8; ++h) {
    bool on = lane < 10;
    float logit = on ? lg[row][h * 26 + 16 + lane] : -3.0e38f;
    float y = on ? (logit + gg[row][h * 26 + 16 + lane]) : -3.0e38f;
    float v = y; int idx = lane;
    for (int off = 8; off; off >>= 1) {
      float v2 = __shfl_xor(v, off, 16);
      int i2 = __shfl_xor(idx, off, 16);
      if (v2 > v || (v2 == v && i2 < idx)) { v = v2; idx = i2; }
    }
    float m = logit;
    for (int off = 8; off; off >>= 1) m = fmaxf(m, __shfl_xor(m, off, 16));
    float sh = logit - m;
    double s = on ? exp((double)sh) : 0.0;
    for (int off = 8; off; off >>= 1) s += __shfl_xor(s, off, 16);
    float sha = __shfl(sh, idx, 16);
    double lp = (double)sha - log(s);
    int ah = __shfl(av, 8 + h, 16);
    if (ah > 0) lpsum += lp;
    if (lane == 8 + h) my_act = (ah > 0) ? (float)idx : -1.0f;
  }

  // ---- stores (all float32) ----
  out[(size_t)gb * 16 + lane] = my_act;                                // actions
  if (lane == 0) out[(size_t)B_TOTAL * 16 + gb] = (float)lpsum;        // logp sum
  out[(size_t)B_TOTAL * 17 + (size_t)gb * 16 + lane] = (float)av;      // avail
}

extern "C" void kernel_launch(void* const* d_in, const int* in_sizes, int n_in,
                              void* d_out, int out_size, void* d_ws, size_t ws_size,
                              hipStream_t stream) {
  const float* x    = (const float*)d_in[0];
  const int*   av   = (const int*)  d_in[1];
  const float* Wsc  = (const float*)d_in[2];
  const float* bsc  = (const float*)d_in[3];
  const float* Wpow = (const float*)d_in[4];
  const float* bpow = (const float*)d_in[5];
  float* outp = (float*)d_out;

  float* Wp = (float*)d_ws;          // 256*256 floats
  float* bp = Wp + 65536;            // 256 floats

  repack_kernel<<<257, 256, 0, stream>>>(Wsc, bsc, Wpow, bpow, Wp, bp);
  act_kernel<<<B_TOTAL / 16, 256, 0, stream>>>(x, av, Wp, bp, outp);
}

// Round 4
// 868.395 us; speedup vs baseline: 1.0311x; 1.0311x over previous
//
#include <hip/hip_runtime.h>

// ---------------------------------------------------------------------------
// MultiDiscreteACTLayer: B=131072 rows, D=256.
// Per row: 8 users x 16 sc logits + 8 heads x 10 pow logits = 208 dots of 256.
// JAX threefry, PARTITIONABLE semantics (jax>=0.4.36 default):
//   split(key,8)[u] = threefry2x32(key, (0, u))          (foldlike, both words)
//   fold_in(key, d) = threefry2x32(key, (0, d))          (both words)
//   random_bits 32-bit, element i: (b1,b2)=tf2(key,(0,i)); bits = b1 ^ b2
// Output (float32): actions (B,16) | logp_sum (B,1) | avail (B,16).
// R4: LDS union (gg aliases xs) 43->29.7KB => 5 blocks/CU; GEMM K-loop
//     restructured to 4-k steps with ds_read_b128 + hoisted w loads.
// ---------------------------------------------------------------------------

#define B_TOTAL 131072
#define NCOL    208      // 8 users * (16 sc + 10 pow)
#define NCOLP   256      // padded column count for uniform 4x4 tiling
#define TINYF   1.17549435e-38f

struct TF2 { unsigned a, b; };

__host__ __device__ constexpr unsigned rotl_(unsigned x, int r) {
  return (x << r) | (x >> (32 - r));
}

// Threefry-2x32, 20 rounds, exactly as JAX/Random123.
__host__ __device__ constexpr TF2 tf2(unsigned k0, unsigned k1, unsigned x0, unsigned x1) {
  unsigned ks0 = k0, ks1 = k1, ks2 = k0 ^ k1 ^ 0x1BD11BDAu;
  x0 += ks0; x1 += ks1;
  x0 += x1; x1 = rotl_(x1, 13); x1 ^= x0;
  x0 += x1; x1 = rotl_(x1, 15); x1 ^= x0;
  x0 += x1; x1 = rotl_(x1, 26); x1 ^= x0;
  x0 += x1; x1 = rotl_(x1,  6); x1 ^= x0;
  x0 += ks1; x1 += ks2 + 1u;
  x0 += x1; x1 = rotl_(x1, 17); x1 ^= x0;
  x0 += x1; x1 = rotl_(x1, 29); x1 ^= x0;
  x0 += x1; x1 = rotl_(x1, 16); x1 ^= x0;
  x0 += x1; x1 = rotl_(x1, 24); x1 ^= x0;
  x0 += ks2; x1 += ks0 + 2u;
  x0 += x1; x1 = rotl_(x1, 13); x1 ^= x0;
  x0 += x1; x1 = rotl_(x1, 15); x1 ^= x0;
  x0 += x1; x1 = rotl_(x1, 26); x1 ^= x0;
  x0 += x1; x1 = rotl_(x1,  6); x1 ^= x0;
  x0 += ks0; x1 += ks1 + 3u;
  x0 += x1; x1 = rotl_(x1, 17); x1 ^= x0;
  x0 += x1; x1 = rotl_(x1, 29); x1 ^= x0;
  x0 += x1; x1 = rotl_(x1, 16); x1 ^= x0;
  x0 += x1; x1 = rotl_(x1, 24); x1 ^= x0;
  x0 += ks1; x1 += ks2 + 4u;
  x0 += x1; x1 = rotl_(x1, 13); x1 ^= x0;
  x0 += x1; x1 = rotl_(x1, 15); x1 ^= x0;
  x0 += x1; x1 = rotl_(x1, 26); x1 ^= x0;
  x0 += x1; x1 = rotl_(x1,  6); x1 ^= x0;
  x0 += ks2; x1 += ks0 + 5u;
  return TF2{x0, x1};
}

// foldlike derivation from root key (0, 42)
__host__ __device__ constexpr unsigned key_a(unsigned d) { return tf2(0u, 42u, 0u, d).a; }
__host__ __device__ constexpr unsigned key_b(unsigned d) { return tf2(0u, 42u, 0u, d).b; }

// sc_keys[u] = split(key(42), 8)[u]  (partitionable/foldlike)
__device__ const unsigned g_SK0[8] = {
  key_a(0), key_a(1), key_a(2), key_a(3), key_a(4), key_a(5), key_a(6), key_a(7)
};
__device__ const unsigned g_SK1[8] = {
  key_b(0), key_b(1), key_b(2), key_b(3), key_b(4), key_b(5), key_b(6), key_b(7)
};
// pow_key = fold_in(key(42), 999)
constexpr unsigned PK0 = key_a(999);
constexpr unsigned PK1 = key_b(999);

// JAX gumbel from raw bits, fp32 ops replicated; logs via double (correctly
// rounded fp32 result).
__device__ __forceinline__ float gumbelf(unsigned bits) {
  float u = __uint_as_float((bits >> 9) | 0x3f800000u) - 1.0f;   // [0,1)
  u = u + TINYF;               // u*(1-tiny)+tiny with (1-tiny)==1.0f in fp32
  u = fmaxf(TINYF, u);
  float nl = -(float)log((double)u);       // -log(u) > 0
  return -(float)log((double)nl);
}

// ---------------------------------------------------------------------------
// Kernel 0: repack W_sc (8,256,16) + W_pow (8,256,10) -> Wp[k][c], c in [0,256)
// (cols 208..255 zero), plus packed bias bp[256]. Column c = u*26 + n,
// n<16 -> sc logit n, n in 16..25 -> pow logit n-16.
// ---------------------------------------------------------------------------
__global__ void repack_kernel(const float* __restrict__ Wsc, const float* __restrict__ bsc,
                              const float* __restrict__ Wpow, const float* __restrict__ bpow,
                              float* __restrict__ Wp, float* __restrict__ bp) {
  int t = blockIdx.x * 256 + threadIdx.x;   // [0, 65792)
  if (t < 65536) {
    int k = t >> 8, c = t & 255;
    float v = 0.f;
    if (c < NCOL) {
      int u = c / 26, n = c % 26;
      v = (n < 16) ? Wsc[(u * 256 + k) * 16 + n]
                   : Wpow[(u * 256 + k) * 10 + (n - 16)];
    }
    Wp[k * NCOLP + c] = v;
  } else {
    int c = t - 65536;
    float v = 0.f;
    if (c < NCOL) {
      int u = c / 26, n = c % 26;
      v = (n < 16) ? bsc[u * 16 + n] : bpow[u * 10 + (n - 16)];
    }
    bp[c] = v;
  }
}

// ---------------------------------------------------------------------------
// Main kernel: each block handles 16 consecutive rows.
// Phase A: fp64-accum GEMM 16 rows x 256 padded cols (4x4 register tiles),
//          K-loop in 4-k steps: ds_read_b128 for x, hoisted w float4 loads.
// Phase B: threefry+gumbel into LDS (gg aliases xs, dead after Phase A).
// Phase C: 16 lanes per row: sc masked scan (8 users) + pow heads (8).
// ---------------------------------------------------------------------------
__global__ __launch_bounds__(256) void act_kernel(
    const float* __restrict__ x, const int* __restrict__ avail,
    const float* __restrict__ Wp, const float* __restrict__ bp,
    float* __restrict__ out) {
  // gg reuses xs's storage: xs is only read during Phase A, gg is only
  // written in Phase B (after a barrier) and read in Phase C.
  __shared__ __align__(16) union SMem {
    float xs[16][256];     // 16 KB (Phase A)
    float gg[16][NCOL];    // 13.3 KB (Phase B/C)
  } sm;
  __shared__ float lg[16][NCOL];

  const int t = threadIdx.x;
  const int b0 = blockIdx.x * 16;

  // ---- load x tile (16 rows x 256) as float4 ----
#pragma unroll
  for (int i = 0; i < 4; ++i) {
    int flat = t + 256 * i;            // float4 index, [0,1024)
    int r = flat >> 6;                 // 64 float4 per row
    int kq = flat & 63;
    ((float4*)(&sm.xs[r][0]))[kq] = ((const float4*)(x + (size_t)(b0 + r) * 256))[kq];
  }
  __syncthreads();

  // ---- Phase A: GEMM, fp64 accumulate, 4-k steps ----
  {
    const int tr = t >> 6;             // row-group 0..3 (== wave id)
    const int tc = t & 63;             // col-group 0..63
    double acc[4][4] = {};
    const float4* wrow = (const float4*)Wp + tc;   // + k*64 each step
    for (int k4 = 0; k4 < 256; k4 += 4) {
      // hoisted global loads: w for k4..k4+3 (issue first, wait later)
      float4 w4[4];
#pragma unroll
      for (int kk = 0; kk < 4; ++kk) w4[kk] = wrow[(k4 + kk) * 64];
      // x fragments: one ds_read_b128 per row
      float xf[4][4];
#pragma unroll
      for (int rr = 0; rr < 4; ++rr) {
        float4 v = *((const float4*)&sm.xs[tr * 4 + rr][k4]);
        xf[rr][0] = v.x; xf[rr][1] = v.y; xf[rr][2] = v.z; xf[rr][3] = v.w;
      }
#pragma unroll
      for (int kk = 0; kk < 4; ++kk) {
        double w0 = (double)w4[kk].x, w1 = (double)w4[kk].y,
               w2 = (double)w4[kk].z, w3 = (double)w4[kk].w;
#pragma unroll
        for (int rr = 0; rr < 4; ++rr) {
          double xv = (double)xf[rr][kk];
          acc[rr][0] = fma(xv, w0, acc[rr][0]);
          acc[rr][1] = fma(xv, w1, acc[rr][1]);
          acc[rr][2] = fma(xv, w2, acc[rr][2]);
          acc[rr][3] = fma(xv, w3, acc[rr][3]);
        }
      }
    }
#pragma unroll
    for (int rr = 0; rr < 4; ++rr)
#pragma unroll
      for (int cc = 0; cc < 4; ++cc) {
        int c = tc * 4 + cc;
        if (c < NCOL)
          lg[tr * 4 + rr][c] = (float)(acc[rr][cc] + (double)bp[c]);
      }
  }
  __syncthreads();   // all xs reads done before gg (aliased) is written

  // ---- Phase B: gumbels, partitionable counter mode (bits = w0 ^ w1) ----
  // 16 rows x 208 cols = 3328 = 13 * 256 elements.
  // sc element (user u, row gb, cat n):   i = gb*16+n,        key SK[u]
  // pow element (row gb, head h, cat j):  i = gb*80+h*10+j,   key PK
#pragma unroll
  for (int i = 0; i < 13; ++i) {
    int idx = t + 256 * i;             // [0, 3328)
    int row = idx / 208, c = idx % 208;
    int u = c / 26, n = c % 26;
    unsigned gbr = (unsigned)(b0 + row);
    unsigned k0, k1, cnt;
    if (n < 16) { k0 = g_SK0[u]; k1 = g_SK1[u]; cnt = gbr * 16u + (unsigned)n; }
    else        { k0 = PK0;      k1 = PK1;      cnt = gbr * 80u + (unsigned)(u * 10 + n - 16); }
    TF2 r = tf2(k0, k1, 0u, cnt);
    sm.gg[row][c] = gumbelf(r.a ^ r.b);
  }
  __syncthreads();

  // ---- Phase C: sampling. 16 lanes per row. ----
  const int row = t >> 4;
  const int lane = t & 15;
  const int gb = b0 + row;
  const int av = avail[gb * 16 + lane];   // my lane's avail column
  int stat = 0;                           // sc_stat for category `lane`
  double lpsum = 0.0;
  float my_act = 0.0f;

  // sc scan: 8 users, sequential (sc_stat dependency)
  for (int u = 0; u < 8; ++u) {
    float logit = lg[row][u * 26 + lane];
    float ml = (stat < 2) ? logit : -1e10f;          // masked logit
    float y = ml + sm.gg[row][u * 26 + lane];        // gumbel-perturbed
    // argmax (first index on tie)
    float v = y; int idx = lane;
    for (int off = 8; off; off >>= 1) {
      float v2 = __shfl_xor(v, off, 16);
      int i2 = __shfl_xor(idx, off, 16);
      if (v2 > v || (v2 == v && i2 < idx)) { v = v2; idx = i2; }
    }
    // log-softmax denom over masked logits
    float m = ml;
    for (int off = 8; off; off >>= 1) m = fmaxf(m, __shfl_xor(m, off, 16));
    float sh = ml - m;                               // fp32 shifted
    double s = exp((double)sh);                      // exp(-1e10)=0 for masked
    for (int off = 8; off; off >>= 1) s += __shfl_xor(s, off, 16);
    float sha = __shfl(sh, idx, 16);
    double lp = (double)sha - log(s);
    int au = __shfl(av, u, 16);
    if (au > 0) {
      lpsum += lp;
      if (lane == idx) stat += 1;                    // sc_stat update
    }
    if (lane == u) my_act = (au > 0) ? (float)idx : -1.0f;
  }

  // pow heads: independent
  for (int h = 0; h < 8; ++h) {
    bool on = lane < 10;
    float logit = on ? lg[row][h * 26 + 16 + lane] : -3.0e38f;
    float y = on ? (logit + sm.gg[row][h * 26 + 16 + lane]) : -3.0e38f;
    float v = y; int idx = lane;
    for (int off = 8; off; off >>= 1) {
      float v2 = __shfl_xor(v, off, 16);
      int i2 = __shfl_xor(idx, off, 16);
      if (v2 > v || (v2 == v && i2 < idx)) { v = v2; idx = i2; }
    }
    float m = logit;
    for (int off = 8; off; off >>= 1) m = fmaxf(m, __shfl_xor(m, off, 16));
    float sh = logit - m;
    double s = on ? exp((double)sh) : 0.0;
    for (int off = 8; off; off >>= 1) s += __shfl_xor(s, off, 16);
    float sha = __shfl(sh, idx, 16);
    double lp = (double)sha - log(s);
    int ah = __shfl(av, 8 + h, 16);
    if (ah > 0) lpsum += lp;
    if (lane == 8 + h) my_act = (ah > 0) ? (float)idx : -1.0f;
  }

  // ---- stores (all float32) ----
  out[(size_t)gb * 16 + lane] = my_act;                                // actions
  if (lane == 0) out[(size_t)B_TOTAL * 16 + gb] = (float)lpsum;        // logp sum
  out[(size_t)B_TOTAL * 17 + (size_t)gb * 16 + lane] = (float)av;      // avail
}

extern "C" void kernel_launch(void* const* d_in, const int* in_sizes, int n_in,
                              void* d_out, int out_size, void* d_ws, size_t ws_size,
                              hipStream_t stream) {
  const float* x    = (const float*)d_in[0];
  const int*   av   = (const int*)  d_in[1];
  const float* Wsc  = (const float*)d_in[2];
  const float* bsc  = (const float*)d_in[3];
  const float* Wpow = (const float*)d_in[4];
  const float* bpow = (const float*)d_in[5];
  float* outp = (float*)d_out;

  float* Wp = (float*)d_ws;          // 256*256 floats
  float* bp = Wp + 65536;            // 256 floats

  repack_kernel<<<257, 256, 0, stream>>>(Wsc, bsc, Wpow, bpow, Wp, bp);
  act_kernel<<<B_TOTAL / 16, 256, 0, stream>>>(x, av, Wp, bp, outp);
}